// Round 3
// baseline (395.533 us; speedup 1.0000x reference)
//
#include <hip/hip_runtime.h>

// Problem constants
#define Vn 128
#define Sn 32
#define En 16
#define M0 128
#define Ln 128
#define Bn 16
#define Nn 127
#define NROWS (Bn * Nn)     // 2032 output rows
#define NBLK (NROWS / 2)    // 1016 blocks, 2 rows per block -> single occupancy round
#define TRS 36              // combined sb|ob table row stride (dwords), 16B-aligned, bank-rotating

__global__ __launch_bounds__(256, 4) void memnet_fused(
    const float* __restrict__ node_fts, const float* __restrict__ edge_fts,
    const float* __restrict__ graph_fts, const float* __restrict__ adjm,
    const float* __restrict__ enc, const float* __restrict__ qb,
    const float* __restrict__ sb, const float* __restrict__ ob,
    const float* __restrict__ mc, const float* __restrict__ wout,
    const float* __restrict__ wfin, float* __restrict__ out)
{
    __shared__ __align__(16) float tbl[M0 * TRS];   // [sb(16) | ob(16) | pad(4)] per vocab row
    __shared__ __align__(16) float encL[Sn * En];
    __shared__ float scoresL[M0];
    __shared__ float probsL[M0];
    __shared__ float uL[En];
    __shared__ float ugL[En];
    __shared__ float uoL[En];
    __shared__ float cM[En];    // sb[0][e] * sum_s enc[s][e]
    __shared__ float cC[En];    // ob[0][e] * sum_s enc[s][e]
    __shared__ float xL[Ln];
    __shared__ float xgL[Ln];
    __shared__ float xg2L[Vn];
    __shared__ float owaveL[4 * En];
    __shared__ float red[4], red2[4];
    __shared__ int listL[128];
    __shared__ int flagL[128];
    __shared__ int wcnt[2];

    const int t = threadIdx.x;
    const int lane = t & 63;
    const int wv = t >> 6;

    // ---- once per block: stage combined sb|ob table, enc, const rows ----
    for (int c = t; c < 1024; c += 256) {
        int r = c >> 3, q = c & 7;
        float4 v = make_float4(0.f, 0.f, 0.f, 0.f);
        if (r < 127)
            v = *(const float4*)((q < 4) ? &sb[r * 16 + q * 4]
                                         : &ob[r * 16 + (q - 4) * 4]);
        *(float4*)&tbl[r * TRS + q * 4] = v;
    }
    if (t < 128) *(float4*)&encL[t * 4] = *(const float4*)&enc[t * 4];
    if (wv == 1 && lane < 16) {
        float es = 0.f;
        for (int s = 0; s < 32; s++) es += enc[s * 16 + lane];
        cM[lane] = sb[lane] * es;   // vocab row 0
        cC[lane] = ob[lane] * es;
    }

    for (int rr = 0; rr < 2; rr++) {
        const int bt = blockIdx.x * 2 + rr;     // output row == b*127 + i
        const int b = bt / 127;

        // ---- per-row: active flags + compacted list; u (wave0) / u_g (wave2) ----
        if (t < 128) {
            bool flag = (t < 127) && (adjm[(size_t)bt * 127 + t] != 0.f);
            unsigned long long msk = __ballot(flag);
            int pos = (int)__popcll(msk & ((1ull << lane) - 1ull));
            if (flag) listL[(t & 64) + pos] = t;   // wave0 -> [0..), wave1 -> [64..)
            if (lane == 0) wcnt[t >> 6] = (int)__popcll(msk);
            flagL[t] = flag ? 1 : 0;
        }
        if (lane < 16) {
            if (wv == 0) {
                float ue = 0.f;
                for (int s = 0; s < 32; s++) {
                    int qi = (int)node_fts[(size_t)bt * 32 + s];
                    if (qi < 0) qi = 0;
                    float w = (qi < 127) ? qb[qi * 16 + lane] : 0.f;
                    ue = fmaf(w, enc[s * 16 + lane], ue);
                }
                uL[lane] = ue;
            } else if (wv == 2) {
                float ue = 0.f;
                for (int s = 0; s < 32; s++) {
                    int qi = (int)graph_fts[b * 32 + s];
                    if (qi < 0) qi = 0;
                    float w = (qi < 127) ? qb[qi * 16 + lane] : 0.f;
                    ue = fmaf(w, enc[s * 16 + lane], ue);
                }
                ugL[lane] = ue;
            }
        }
        __syncthreads();

        // ---- masked/pad slots: closed-form scores ----
        if (t < 128 && !flagL[t]) {
            float p = 0.f;
#pragma unroll
            for (int e4 = 0; e4 < 16; e4 += 4) {
                float4 m4 = *(const float4*)&mc[t * 16 + e4];
                p = fmaf(cM[e4 + 0] + m4.x, uL[e4 + 0], p);
                p = fmaf(cM[e4 + 1] + m4.y, uL[e4 + 1], p);
                p = fmaf(cM[e4 + 2] + m4.z, uL[e4 + 2], p);
                p = fmaf(cM[e4 + 3] + m4.w, uL[e4 + 3], p);
            }
            scoresL[t] = p;
        }

        // ---- gather: one active slot per quad; edge indices via direct load + quad shfl ----
        const int eg4 = (t & 3) * 4;
        const int qd = t >> 2;              // quad id 0..63
        const int qbase = lane & ~3;        // quad base lane within wave
        const int c0 = wcnt[0];
        const int nact = c0 + wcnt[1];
        const float4 u4 = *(const float4*)&uL[eg4];

        float4 aC_A = make_float4(0.f, 0.f, 0.f, 0.f);
        float4 aC_B = make_float4(0.f, 0.f, 0.f, 0.f);
        int mA = -1, mB = -1;

        if (qd < nact) {
            mA = listL[(qd < c0) ? qd : (qd - c0 + 64)];
            const float* er = &edge_fts[(size_t)(bt * 127 + mA) * 32];
            float4 fa = *(const float4*)&er[(t & 3) * 4];
            float4 fb = *(const float4*)&er[16 + (t & 3) * 4];
            unsigned pk0 = (unsigned)(int)fa.x | ((unsigned)(int)fa.y << 8)
                         | ((unsigned)(int)fa.z << 16) | ((unsigned)(int)fa.w << 24);
            unsigned pk1 = (unsigned)(int)fb.x | ((unsigned)(int)fb.y << 8)
                         | ((unsigned)(int)fb.z << 16) | ((unsigned)(int)fb.w << 24);
            float4 aM = make_float4(0.f, 0.f, 0.f, 0.f);
            for (int sq = 0; sq < 8; sq++) {
                unsigned w0 = __shfl((sq < 4) ? pk0 : pk1, qbase + (sq & 3));
#pragma unroll
                for (int j = 0; j < 4; j++) {
                    int s = sq * 4 + j;
                    int i0 = (w0 >> (8 * j)) & 0xFF;
                    float4 eb = *(const float4*)&encL[s * 16 + eg4];
                    const float* rp = &tbl[i0 * TRS + eg4];
                    float4 a0 = *(const float4*)rp;
                    float4 c0v = *(const float4*)(rp + 16);
                    aM.x = fmaf(a0.x, eb.x, aM.x); aM.y = fmaf(a0.y, eb.y, aM.y);
                    aM.z = fmaf(a0.z, eb.z, aM.z); aM.w = fmaf(a0.w, eb.w, aM.w);
                    aC_A.x = fmaf(c0v.x, eb.x, aC_A.x); aC_A.y = fmaf(c0v.y, eb.y, aC_A.y);
                    aC_A.z = fmaf(c0v.z, eb.z, aC_A.z); aC_A.w = fmaf(c0v.w, eb.w, aC_A.w);
                }
            }
            float4 mc4 = *(const float4*)&mc[mA * 16 + eg4];
            float p = (aM.x + mc4.x) * u4.x + (aM.y + mc4.y) * u4.y
                    + (aM.z + mc4.z) * u4.z + (aM.w + mc4.w) * u4.w;
            p += __shfl_xor(p, 1); p += __shfl_xor(p, 2);
            if ((t & 3) == 0) scoresL[mA] = p;
        }
        if (qd + 64 < nact) {   // overflow slots (nact > 64), concentrated in wave 0
            int g = qd + 64;
            mB = listL[(g < c0) ? g : (g - c0 + 64)];
            const float* er = &edge_fts[(size_t)(bt * 127 + mB) * 32];
            float4 fa = *(const float4*)&er[(t & 3) * 4];
            float4 fb = *(const float4*)&er[16 + (t & 3) * 4];
            unsigned pk0 = (unsigned)(int)fa.x | ((unsigned)(int)fa.y << 8)
                         | ((unsigned)(int)fa.z << 16) | ((unsigned)(int)fa.w << 24);
            unsigned pk1 = (unsigned)(int)fb.x | ((unsigned)(int)fb.y << 8)
                         | ((unsigned)(int)fb.z << 16) | ((unsigned)(int)fb.w << 24);
            float4 aM = make_float4(0.f, 0.f, 0.f, 0.f);
            for (int sq = 0; sq < 8; sq++) {
                unsigned w0 = __shfl((sq < 4) ? pk0 : pk1, qbase + (sq & 3));
#pragma unroll
                for (int j = 0; j < 4; j++) {
                    int s = sq * 4 + j;
                    int i0 = (w0 >> (8 * j)) & 0xFF;
                    float4 eb = *(const float4*)&encL[s * 16 + eg4];
                    const float* rp = &tbl[i0 * TRS + eg4];
                    float4 a0 = *(const float4*)rp;
                    float4 c0v = *(const float4*)(rp + 16);
                    aM.x = fmaf(a0.x, eb.x, aM.x); aM.y = fmaf(a0.y, eb.y, aM.y);
                    aM.z = fmaf(a0.z, eb.z, aM.z); aM.w = fmaf(a0.w, eb.w, aM.w);
                    aC_B.x = fmaf(c0v.x, eb.x, aC_B.x); aC_B.y = fmaf(c0v.y, eb.y, aC_B.y);
                    aC_B.z = fmaf(c0v.z, eb.z, aC_B.z); aC_B.w = fmaf(c0v.w, eb.w, aC_B.w);
                }
            }
            float4 mc4 = *(const float4*)&mc[mB * 16 + eg4];
            float p = (aM.x + mc4.x) * u4.x + (aM.y + mc4.y) * u4.y
                    + (aM.z + mc4.z) * u4.z + (aM.w + mc4.w) * u4.w;
            p += __shfl_xor(p, 1); p += __shfl_xor(p, 2);
            if ((t & 3) == 0) scoresL[mB] = p;
        }
        __syncthreads();

        // ---- softmax over 128 slots (+ masked prob mass in same reduction) ----
        float pmask;
        {
            float v = (t < 128) ? scoresL[t] : -1e30f;
#pragma unroll
            for (int off = 32; off > 0; off >>= 1) v = fmaxf(v, __shfl_xor(v, off));
            if (lane == 0) red[wv] = v;
            __syncthreads();
            float mx = fmaxf(fmaxf(red[0], red[1]), fmaxf(red[2], red[3]));
            float ex = (t < 128) ? __expf(scoresL[t] - mx) : 0.f;
            float exm = (t < 128 && !flagL[t]) ? ex : 0.f;
            float sv = ex, sm = exm;
#pragma unroll
            for (int off = 32; off > 0; off >>= 1) {
                sv += __shfl_xor(sv, off);
                sm += __shfl_xor(sm, off);
            }
            __syncthreads();
            if (lane == 0) { red[wv] = sv; red2[wv] = sm; }
            __syncthreads();
            float sum = red[0] + red[1] + red[2] + red[3];
            pmask = (red2[0] + red2[1] + red2[2] + red2[3]) / sum;
            if (t < 128) probsL[t] = ex / sum;
        }
        __syncthreads();

        // ---- o_active: probs-weighted Cj from registers, shfl-tree reduce ----
        {
            float4 op = make_float4(0.f, 0.f, 0.f, 0.f);
            if (mA >= 0) {
                float pa = probsL[mA];
                op.x = pa * aC_A.x; op.y = pa * aC_A.y;
                op.z = pa * aC_A.z; op.w = pa * aC_A.w;
            }
            if (mB >= 0) {
                float pb = probsL[mB];
                op.x = fmaf(pb, aC_B.x, op.x); op.y = fmaf(pb, aC_B.y, op.y);
                op.z = fmaf(pb, aC_B.z, op.z); op.w = fmaf(pb, aC_B.w, op.w);
            }
#pragma unroll
            for (int off = 4; off <= 32; off <<= 1) {
                op.x += __shfl_xor(op.x, off);
                op.y += __shfl_xor(op.y, off);
                op.z += __shfl_xor(op.z, off);
                op.w += __shfl_xor(op.w, off);
            }
            if (lane < 4) *(float4*)&owaveL[wv * 16 + lane * 4] = op;
        }
        __syncthreads();
        if (t < 16) {
            float o = owaveL[t] + owaveL[16 + t] + owaveL[32 + t] + owaveL[48 + t];
            uoL[t] = uL[t] + o + cC[t] * pmask;
        }
        __syncthreads();

        // ---- x = relu(uo @ W_out) (half 0); xg = relu((u_g + cC) @ W_out) (half 1) ----
        if (t < 128) {
            float acc = 0.f;
#pragma unroll
            for (int e = 0; e < 16; e++) acc = fmaf(uoL[e], wout[e * 128 + t], acc);
            xL[t] = fmaxf(acc, 0.f);
        } else {
            int l = t - 128;
            float acc = 0.f;
#pragma unroll
            for (int e = 0; e < 16; e++) acc = fmaf(ugL[e] + cC[e], wout[e * 128 + l], acc);
            xgL[l] = fmaxf(acc, 0.f);
        }
        __syncthreads();

        // ---- ret = x @ W_fin (half 0); ret127 = xg @ W_fin (half 1); out = sum ----
        {
            const int vcol = t & 127;
            const float* xsrc = (t < 128) ? xL : xgL;   // wave-uniform base
            float acc = 0.f;
            for (int l = 0; l < 128; l++) acc = fmaf(xsrc[l], wfin[l * 128 + vcol], acc);
            if (t >= 128) xg2L[vcol] = acc;
            __syncthreads();
            if (t < 128) out[(size_t)bt * 128 + vcol] = acc + xg2L[vcol];
        }
        __syncthreads();   // protect shared buffers before next row's writes
    }
}

extern "C" void kernel_launch(void* const* d_in, const int* in_sizes, int n_in,
                              void* d_out, int out_size, void* d_ws, size_t ws_size,
                              hipStream_t stream)
{
    const float* node  = (const float*)d_in[0];
    const float* edge  = (const float*)d_in[1];
    const float* graph = (const float*)d_in[2];
    const float* adjm  = (const float*)d_in[3];
    // d_in[4] = hidden (unused)
    const float* enc   = (const float*)d_in[5];
    const float* qb    = (const float*)d_in[6];
    const float* sb    = (const float*)d_in[7];
    const float* ob    = (const float*)d_in[8];
    const float* mc    = (const float*)d_in[9];
    // d_in[10] = W_int (unused, num_hops == 1)
    const float* wout  = (const float*)d_in[11];
    const float* wfin  = (const float*)d_in[12];

    memnet_fused<<<NBLK, 256, 0, stream>>>(node, edge, graph, adjm, enc, qb,
                                           sb, ob, mc, wout, wfin, (float*)d_out);
}

// Round 4
// 394.477 us; speedup vs baseline: 1.0027x; 1.0027x over previous
//
#include <hip/hip_runtime.h>

// Problem constants
#define Vn 128
#define Sn 32
#define En 16
#define M0 128
#define Ln 128
#define Bn 16
#define Nn 127
#define NROWS (Bn * Nn)     // 2032 output rows
#define NBLK (NROWS / 2)    // 1016 blocks, 2 rows per block -> single occupancy round
#define TRS 36              // combined sb|ob table row stride (dwords)

__global__ __launch_bounds__(256, 4) void memnet_fused(
    const float* __restrict__ node_fts, const float* __restrict__ edge_fts,
    const float* __restrict__ graph_fts, const float* __restrict__ adjm,
    const float* __restrict__ enc, const float* __restrict__ qb,
    const float* __restrict__ sb, const float* __restrict__ ob,
    const float* __restrict__ mc, const float* __restrict__ wout,
    const float* __restrict__ wfin, float* __restrict__ out)
{
    __shared__ __align__(16) float tbl[M0 * TRS];   // [sb(16) | ob(16) | pad(4)] per vocab row
    __shared__ __align__(16) float encL[Sn * En];
    __shared__ unsigned int idxw[M0 * 8];           // 32 uint8 idx per slot, packed
    __shared__ float scoresL[M0];
    __shared__ float probsL[M0];
    __shared__ float uL[En];
    __shared__ float ugL[En];
    __shared__ float uoL[En];
    __shared__ float cM[En];    // sb[0][e] * sum_s enc[s][e]
    __shared__ float cC[En];    // ob[0][e] * sum_s enc[s][e]
    __shared__ float xL[Ln];
    __shared__ float xgL[Ln];
    __shared__ float xg2L[Vn];
    __shared__ float owaveL[4 * En];
    __shared__ float red[4], red2[4];
    __shared__ int listL[128];
    __shared__ int flagL[128];
    __shared__ int wcnt[2];

    const int t = threadIdx.x;
    const int lane = t & 63;
    const int wv = t >> 6;

    // ---- once per block: stage combined sb|ob table, enc, const rows ----
    for (int c = t; c < 1024; c += 256) {
        int r = c >> 3, q = c & 7;
        float4 v = make_float4(0.f, 0.f, 0.f, 0.f);
        if (r < 127)
            v = *(const float4*)((q < 4) ? &sb[r * 16 + q * 4]
                                         : &ob[r * 16 + (q - 4) * 4]);
        *(float4*)&tbl[r * TRS + q * 4] = v;
    }
    if (t < 128) *(float4*)&encL[t * 4] = *(const float4*)&enc[t * 4];
    if (wv == 1 && lane < 16) {
        float es = 0.f;
        for (int s = 0; s < 32; s++) es += enc[s * 16 + lane];
        cM[lane] = sb[lane] * es;   // vocab row 0
        cC[lane] = ob[lane] * es;
    }

    for (int rr = 0; rr < 2; rr++) {
        const int bt = blockIdx.x * 2 + rr;     // output row == b*127 + i
        const int b = bt / 127;

        // ---- per-row: active flags + ballot-compacted slot list ----
        if (t < 128) {
            bool flag = (t < 127) && (adjm[(size_t)bt * 127 + t] != 0.f);
            unsigned long long msk = __ballot(flag);
            int pos = (int)__popcll(msk & ((1ull << lane) - 1ull));
            if (flag) listL[(t & 64) + pos] = t;   // wave0 -> [0..), wave1 -> [64..)
            if (lane == 0) wcnt[t >> 6] = (int)__popcll(msk);
            flagL[t] = flag ? 1 : 0;
        }
        // ---- index tile for active slots only (coalesced streaming read) ----
        for (int c = t; c < 1024; c += 256) {
            int m = c >> 3, q = c & 7;
            if (m < 127 && adjm[(size_t)bt * 127 + m] != 0.f) {
                float4 v = *(const float4*)&edge_fts[(size_t)(bt * 127 + m) * 32 + q * 4];
                idxw[m * 8 + q] = (unsigned)(int)v.x | ((unsigned)(int)v.y << 8)
                                | ((unsigned)(int)v.z << 16) | ((unsigned)(int)v.w << 24);
            }
        }
        // ---- u (wave0) / u_g (wave2) ----
        if (lane < 16) {
            if (wv == 0) {
                float ue = 0.f;
                for (int s = 0; s < 32; s++) {
                    int qi = (int)node_fts[(size_t)bt * 32 + s];
                    if (qi < 0) qi = 0;
                    float w = (qi < 127) ? qb[qi * 16 + lane] : 0.f;
                    ue = fmaf(w, enc[s * 16 + lane], ue);
                }
                uL[lane] = ue;
            } else if (wv == 2) {
                float ue = 0.f;
                for (int s = 0; s < 32; s++) {
                    int qi = (int)graph_fts[b * 32 + s];
                    if (qi < 0) qi = 0;
                    float w = (qi < 127) ? qb[qi * 16 + lane] : 0.f;
                    ue = fmaf(w, enc[s * 16 + lane], ue);
                }
                ugL[lane] = ue;
            }
        }
        __syncthreads();

        // ---- masked/pad slots: closed-form scores ----
        if (t < 128 && !flagL[t]) {
            float p = 0.f;
#pragma unroll
            for (int e4 = 0; e4 < 16; e4 += 4) {
                float4 m4 = *(const float4*)&mc[t * 16 + e4];
                p = fmaf(cM[e4 + 0] + m4.x, uL[e4 + 0], p);
                p = fmaf(cM[e4 + 1] + m4.y, uL[e4 + 1], p);
                p = fmaf(cM[e4 + 2] + m4.z, uL[e4 + 2], p);
                p = fmaf(cM[e4 + 3] + m4.w, uL[e4 + 3], p);
            }
            scoresL[t] = p;
        }

        // ---- gather: one active slot per quad, all 4 waves, idxw from LDS ----
        const int eg4 = (t & 3) * 4;
        const int qd = t >> 2;              // quad id 0..63
        const int c0 = wcnt[0];
        const int nact = c0 + wcnt[1];
        const float4 u4 = *(const float4*)&uL[eg4];

        float4 aC_A = make_float4(0.f, 0.f, 0.f, 0.f);
        float4 aC_B = make_float4(0.f, 0.f, 0.f, 0.f);
        int mA = -1, mB = -1;

        if (qd < nact) {
            mA = listL[(qd < c0) ? qd : (qd - c0 + 64)];
            float4 aM = make_float4(0.f, 0.f, 0.f, 0.f);
            for (int sq = 0; sq < 8; sq++) {
                unsigned w0 = idxw[mA * 8 + sq];
#pragma unroll
                for (int j = 0; j < 4; j++) {
                    int s = sq * 4 + j;
                    int i0 = (w0 >> (8 * j)) & 0xFF;
                    float4 eb = *(const float4*)&encL[s * 16 + eg4];
                    const float* rp = &tbl[i0 * TRS + eg4];
                    float4 a0 = *(const float4*)rp;
                    float4 c0v = *(const float4*)(rp + 16);
                    aM.x = fmaf(a0.x, eb.x, aM.x); aM.y = fmaf(a0.y, eb.y, aM.y);
                    aM.z = fmaf(a0.z, eb.z, aM.z); aM.w = fmaf(a0.w, eb.w, aM.w);
                    aC_A.x = fmaf(c0v.x, eb.x, aC_A.x); aC_A.y = fmaf(c0v.y, eb.y, aC_A.y);
                    aC_A.z = fmaf(c0v.z, eb.z, aC_A.z); aC_A.w = fmaf(c0v.w, eb.w, aC_A.w);
                }
            }
            float4 mc4 = *(const float4*)&mc[mA * 16 + eg4];
            float p = (aM.x + mc4.x) * u4.x + (aM.y + mc4.y) * u4.y
                    + (aM.z + mc4.z) * u4.z + (aM.w + mc4.w) * u4.w;
            p += __shfl_xor(p, 1); p += __shfl_xor(p, 2);
            if ((t & 3) == 0) scoresL[mA] = p;
        }
        if (qd + 64 < nact) {   // overflow slots (nact > 64)
            int g = qd + 64;
            mB = listL[(g < c0) ? g : (g - c0 + 64)];
            float4 aM = make_float4(0.f, 0.f, 0.f, 0.f);
            for (int sq = 0; sq < 8; sq++) {
                unsigned w0 = idxw[mB * 8 + sq];
#pragma unroll
                for (int j = 0; j < 4; j++) {
                    int s = sq * 4 + j;
                    int i0 = (w0 >> (8 * j)) & 0xFF;
                    float4 eb = *(const float4*)&encL[s * 16 + eg4];
                    const float* rp = &tbl[i0 * TRS + eg4];
                    float4 a0 = *(const float4*)rp;
                    float4 c0v = *(const float4*)(rp + 16);
                    aM.x = fmaf(a0.x, eb.x, aM.x); aM.y = fmaf(a0.y, eb.y, aM.y);
                    aM.z = fmaf(a0.z, eb.z, aM.z); aM.w = fmaf(a0.w, eb.w, aM.w);
                    aC_B.x = fmaf(c0v.x, eb.x, aC_B.x); aC_B.y = fmaf(c0v.y, eb.y, aC_B.y);
                    aC_B.z = fmaf(c0v.z, eb.z, aC_B.z); aC_B.w = fmaf(c0v.w, eb.w, aC_B.w);
                }
            }
            float4 mc4 = *(const float4*)&mc[mB * 16 + eg4];
            float p = (aM.x + mc4.x) * u4.x + (aM.y + mc4.y) * u4.y
                    + (aM.z + mc4.z) * u4.z + (aM.w + mc4.w) * u4.w;
            p += __shfl_xor(p, 1); p += __shfl_xor(p, 2);
            if ((t & 3) == 0) scoresL[mB] = p;
        }
        __syncthreads();

        // ---- softmax over 128 slots (+ masked prob mass in same reduction) ----
        float pmask;
        {
            float v = (t < 128) ? scoresL[t] : -1e30f;
#pragma unroll
            for (int off = 32; off > 0; off >>= 1) v = fmaxf(v, __shfl_xor(v, off));
            if (lane == 0) red[wv] = v;
            __syncthreads();
            float mx = fmaxf(fmaxf(red[0], red[1]), fmaxf(red[2], red[3]));
            float ex = (t < 128) ? __expf(scoresL[t] - mx) : 0.f;
            float exm = (t < 128 && !flagL[t]) ? ex : 0.f;
            float sv = ex, sm = exm;
#pragma unroll
            for (int off = 32; off > 0; off >>= 1) {
                sv += __shfl_xor(sv, off);
                sm += __shfl_xor(sm, off);
            }
            __syncthreads();
            if (lane == 0) { red[wv] = sv; red2[wv] = sm; }
            __syncthreads();
            float sum = red[0] + red[1] + red[2] + red[3];
            pmask = (red2[0] + red2[1] + red2[2] + red2[3]) / sum;
            if (t < 128) probsL[t] = ex / sum;
        }
        __syncthreads();

        // ---- o_active: probs-weighted Cj from registers, shfl-tree reduce ----
        {
            float4 op = make_float4(0.f, 0.f, 0.f, 0.f);
            if (mA >= 0) {
                float pa = probsL[mA];
                op.x = pa * aC_A.x; op.y = pa * aC_A.y;
                op.z = pa * aC_A.z; op.w = pa * aC_A.w;
            }
            if (mB >= 0) {
                float pb = probsL[mB];
                op.x = fmaf(pb, aC_B.x, op.x); op.y = fmaf(pb, aC_B.y, op.y);
                op.z = fmaf(pb, aC_B.z, op.z); op.w = fmaf(pb, aC_B.w, op.w);
            }
#pragma unroll
            for (int off = 4; off <= 32; off <<= 1) {
                op.x += __shfl_xor(op.x, off);
                op.y += __shfl_xor(op.y, off);
                op.z += __shfl_xor(op.z, off);
                op.w += __shfl_xor(op.w, off);
            }
            if (lane < 4) *(float4*)&owaveL[wv * 16 + lane * 4] = op;
        }
        __syncthreads();
        if (t < 16) {
            float o = owaveL[t] + owaveL[16 + t] + owaveL[32 + t] + owaveL[48 + t];
            uoL[t] = uL[t] + o + cC[t] * pmask;
        }
        __syncthreads();

        // ---- x = relu(uo @ W_out) (half 0); xg = relu((u_g + cC) @ W_out) (half 1) ----
        if (t < 128) {
            float acc = 0.f;
#pragma unroll
            for (int e = 0; e < 16; e++) acc = fmaf(uoL[e], wout[e * 128 + t], acc);
            xL[t] = fmaxf(acc, 0.f);
        } else {
            int l = t - 128;
            float acc = 0.f;
#pragma unroll
            for (int e = 0; e < 16; e++) acc = fmaf(ugL[e] + cC[e], wout[e * 128 + l], acc);
            xgL[l] = fmaxf(acc, 0.f);
        }
        __syncthreads();

        // ---- ret = x @ W_fin (half 0); ret127 = xg @ W_fin (half 1); out = sum ----
        {
            const int vcol = t & 127;
            const float* xsrc = (t < 128) ? xL : xgL;   // wave-uniform base
            float acc = 0.f;
            for (int l = 0; l < 128; l++) acc = fmaf(xsrc[l], wfin[l * 128 + vcol], acc);
            if (t >= 128) xg2L[vcol] = acc;
            __syncthreads();
            if (t < 128) out[(size_t)bt * 128 + vcol] = acc + xg2L[vcol];
        }
        __syncthreads();   // protect shared buffers before next row's writes
    }
}

extern "C" void kernel_launch(void* const* d_in, const int* in_sizes, int n_in,
                              void* d_out, int out_size, void* d_ws, size_t ws_size,
                              hipStream_t stream)
{
    const float* node  = (const float*)d_in[0];
    const float* edge  = (const float*)d_in[1];
    const float* graph = (const float*)d_in[2];
    const float* adjm  = (const float*)d_in[3];
    // d_in[4] = hidden (unused)
    const float* enc   = (const float*)d_in[5];
    const float* qb    = (const float*)d_in[6];
    const float* sb    = (const float*)d_in[7];
    const float* ob    = (const float*)d_in[8];
    const float* mc    = (const float*)d_in[9];
    // d_in[10] = W_int (unused, num_hops == 1)
    const float* wout  = (const float*)d_in[11];
    const float* wfin  = (const float*)d_in[12];

    memnet_fused<<<NBLK, 256, 0, stream>>>(node, edge, graph, adjm, enc, qb,
                                           sb, ob, mc, wout, wfin, (float*)d_out);
}

// Round 5
// 135.976 us; speedup vs baseline: 2.9088x; 2.9011x over previous
//
#include <hip/hip_runtime.h>

// Problem constants
#define Vn 128
#define Sn 32
#define En 16
#define M0 128
#define Ln 128
#define Bn 16
#define Nn 127
#define NROWS (Bn * Nn)     // 2032 output rows
#define NBLK (NROWS / 2)    // 1016 blocks x 512 threads; 2 rows per block IN PARALLEL
#define TRS 36              // combined sb|ob table row stride (dwords)

__global__ __launch_bounds__(512, 8) void memnet_fused(
    const float* __restrict__ node_fts, const float* __restrict__ edge_fts,
    const float* __restrict__ graph_fts, const float* __restrict__ adjm,
    const float* __restrict__ enc, const float* __restrict__ qb,
    const float* __restrict__ sb, const float* __restrict__ ob,
    const float* __restrict__ mc, const float* __restrict__ wout,
    const float* __restrict__ wfin, float* __restrict__ out)
{
    __shared__ __align__(16) float tbl[M0 * TRS];   // [sb(16) | ob(16) | pad(4)] per vocab row
    __shared__ __align__(16) float encL[Sn * En];
    __shared__ unsigned int idxw[2][M0 * 8];        // per-half packed uint8 indices
    __shared__ float scoresL[2][M0];
    __shared__ float probsL[2][M0];
    __shared__ float uL[2][En];
    __shared__ float ugL[2][En];
    __shared__ float uoL[2][En];
    __shared__ float cM[En];    // sb[0][e] * sum_s enc[s][e]
    __shared__ float cC[En];    // ob[0][e] * sum_s enc[s][e]
    __shared__ float xL[2][Ln];
    __shared__ float xgL[2][Ln];
    __shared__ float xg2L[2][Vn];
    __shared__ float owaveL[8 * En];
    __shared__ float red[8], red2[8];
    __shared__ int listL[2][128];
    __shared__ int flagL[2][128];
    __shared__ int wcnt[2][2];

    const int t = threadIdx.x;
    const int h = t >> 8;           // half 0/1 -> row
    const int ht = t & 255;         // thread-in-half (round-2 "t")
    const int lane = t & 63;
    const int wv = t >> 6;          // global wave 0..7
    const int wl = wv & 3;          // wave-in-half 0..3

    const int bt = blockIdx.x * 2 + h;   // output row == b*127 + i
    const int b = bt / 127;

    // ---- block-wide staging: combined sb|ob table + enc (shared by both halves) ----
    for (int c = t; c < 1024; c += 512) {
        int r = c >> 3, q = c & 7;
        float4 v = make_float4(0.f, 0.f, 0.f, 0.f);
        if (r < 127)
            v = *(const float4*)((q < 4) ? &sb[r * 16 + q * 4]
                                         : &ob[r * 16 + (q - 4) * 4]);
        *(float4*)&tbl[r * TRS + q * 4] = v;
    }
    if (t < 128) *(float4*)&encL[t * 4] = *(const float4*)&enc[t * 4];

    // ---- per-half: active flags + ballot-compacted slot list ----
    if (ht < 128) {
        bool flag = (ht < 127) && (adjm[(size_t)bt * 127 + ht] != 0.f);
        unsigned long long msk = __ballot(flag);
        int pos = (int)__popcll(msk & ((1ull << lane) - 1ull));
        if (flag) listL[h][(ht & 64) + pos] = ht;   // wave a -> [0..), wave b -> [64..)
        if (lane == 0) wcnt[h][ht >> 6] = (int)__popcll(msk);
        flagL[h][ht] = flag ? 1 : 0;
    }
    // ---- index tiles for active slots, both halves (coalesced streaming read) ----
    for (int c = t; c < 2048; c += 512) {
        int hh = c >> 10, m = (c >> 3) & 127, q = c & 7;
        int bth = blockIdx.x * 2 + hh;
        if (m < 127 && adjm[(size_t)bth * 127 + m] != 0.f) {
            float4 v = *(const float4*)&edge_fts[(size_t)(bth * 127 + m) * 32 + q * 4];
            idxw[hh][m * 8 + q] = (unsigned)(int)v.x | ((unsigned)(int)v.y << 8)
                                | ((unsigned)(int)v.z << 16) | ((unsigned)(int)v.w << 24);
        }
    }
    // ---- u (wl 0) / u_g (wl 2) per half; cM/cC on wave 3 ----
    if (lane < 16) {
        if (wl == 0) {
            float ue = 0.f;
            for (int s = 0; s < 32; s++) {
                int qi = (int)node_fts[(size_t)bt * 32 + s];
                if (qi < 0) qi = 0;
                float w = (qi < 127) ? qb[qi * 16 + lane] : 0.f;
                ue = fmaf(w, enc[s * 16 + lane], ue);
            }
            uL[h][lane] = ue;
        } else if (wl == 2) {
            float ue = 0.f;
            for (int s = 0; s < 32; s++) {
                int qi = (int)graph_fts[b * 32 + s];
                if (qi < 0) qi = 0;
                float w = (qi < 127) ? qb[qi * 16 + lane] : 0.f;
                ue = fmaf(w, enc[s * 16 + lane], ue);
            }
            ugL[h][lane] = ue;
        } else if (wv == 3) {
            float es = 0.f;
            for (int s = 0; s < 32; s++) es += enc[s * 16 + lane];
            cM[lane] = sb[lane] * es;   // vocab row 0
            cC[lane] = ob[lane] * es;
        }
    }
    __syncthreads();

    // ---- masked/pad slots: closed-form scores ----
    if (ht < 128 && !flagL[h][ht]) {
        float p = 0.f;
#pragma unroll
        for (int e4 = 0; e4 < 16; e4 += 4) {
            float4 m4 = *(const float4*)&mc[ht * 16 + e4];
            p = fmaf(cM[e4 + 0] + m4.x, uL[h][e4 + 0], p);
            p = fmaf(cM[e4 + 1] + m4.y, uL[h][e4 + 1], p);
            p = fmaf(cM[e4 + 2] + m4.z, uL[h][e4 + 2], p);
            p = fmaf(cM[e4 + 3] + m4.w, uL[h][e4 + 3], p);
        }
        scoresL[h][ht] = p;
    }

    // ---- gather: one active slot per quad, 4 waves per half ----
    const int eg4 = (t & 3) * 4;
    const int qd = ht >> 2;             // quad id 0..63 within half
    const int c0 = wcnt[h][0];
    const int nact = c0 + wcnt[h][1];
    const float4 u4 = *(const float4*)&uL[h][eg4];

    float4 aC_A = make_float4(0.f, 0.f, 0.f, 0.f);
    float4 aC_B = make_float4(0.f, 0.f, 0.f, 0.f);
    int mA = -1, mB = -1;

    if (qd < nact) {
        mA = listL[h][(qd < c0) ? qd : (qd - c0 + 64)];
        float4 aM = make_float4(0.f, 0.f, 0.f, 0.f);
        for (int sq = 0; sq < 8; sq++) {
            unsigned w0 = idxw[h][mA * 8 + sq];
#pragma unroll
            for (int j = 0; j < 4; j++) {
                int s = sq * 4 + j;
                int i0 = (w0 >> (8 * j)) & 0xFF;
                float4 eb = *(const float4*)&encL[s * 16 + eg4];
                const float* rp = &tbl[i0 * TRS + eg4];
                float4 a0 = *(const float4*)rp;
                float4 c0v = *(const float4*)(rp + 16);
                aM.x = fmaf(a0.x, eb.x, aM.x); aM.y = fmaf(a0.y, eb.y, aM.y);
                aM.z = fmaf(a0.z, eb.z, aM.z); aM.w = fmaf(a0.w, eb.w, aM.w);
                aC_A.x = fmaf(c0v.x, eb.x, aC_A.x); aC_A.y = fmaf(c0v.y, eb.y, aC_A.y);
                aC_A.z = fmaf(c0v.z, eb.z, aC_A.z); aC_A.w = fmaf(c0v.w, eb.w, aC_A.w);
            }
        }
        float4 mc4 = *(const float4*)&mc[mA * 16 + eg4];
        float p = (aM.x + mc4.x) * u4.x + (aM.y + mc4.y) * u4.y
                + (aM.z + mc4.z) * u4.z + (aM.w + mc4.w) * u4.w;
        p += __shfl_xor(p, 1); p += __shfl_xor(p, 2);
        if ((t & 3) == 0) scoresL[h][mA] = p;
    }
    if (qd + 64 < nact) {   // overflow slots (nact > 64)
        int g = qd + 64;
        mB = listL[h][(g < c0) ? g : (g - c0 + 64)];
        float4 aM = make_float4(0.f, 0.f, 0.f, 0.f);
        for (int sq = 0; sq < 8; sq++) {
            unsigned w0 = idxw[h][mB * 8 + sq];
#pragma unroll
            for (int j = 0; j < 4; j++) {
                int s = sq * 4 + j;
                int i0 = (w0 >> (8 * j)) & 0xFF;
                float4 eb = *(const float4*)&encL[s * 16 + eg4];
                const float* rp = &tbl[i0 * TRS + eg4];
                float4 a0 = *(const float4*)rp;
                float4 c0v = *(const float4*)(rp + 16);
                aM.x = fmaf(a0.x, eb.x, aM.x); aM.y = fmaf(a0.y, eb.y, aM.y);
                aM.z = fmaf(a0.z, eb.z, aM.z); aM.w = fmaf(a0.w, eb.w, aM.w);
                aC_B.x = fmaf(c0v.x, eb.x, aC_B.x); aC_B.y = fmaf(c0v.y, eb.y, aC_B.y);
                aC_B.z = fmaf(c0v.z, eb.z, aC_B.z); aC_B.w = fmaf(c0v.w, eb.w, aC_B.w);
            }
        }
        float4 mc4 = *(const float4*)&mc[mB * 16 + eg4];
        float p = (aM.x + mc4.x) * u4.x + (aM.y + mc4.y) * u4.y
                + (aM.z + mc4.z) * u4.z + (aM.w + mc4.w) * u4.w;
        p += __shfl_xor(p, 1); p += __shfl_xor(p, 2);
        if ((t & 3) == 0) scoresL[h][mB] = p;
    }
    __syncthreads();

    // ---- softmax over 128 slots per half (+ masked prob mass) ----
    float pmask;
    {
        float v = (ht < 128) ? scoresL[h][ht] : -1e30f;
#pragma unroll
        for (int off = 32; off > 0; off >>= 1) v = fmaxf(v, __shfl_xor(v, off));
        if (lane == 0) red[wv] = v;
        __syncthreads();
        float mx = fmaxf(fmaxf(red[h * 4 + 0], red[h * 4 + 1]),
                         fmaxf(red[h * 4 + 2], red[h * 4 + 3]));
        float ex = (ht < 128) ? __expf(scoresL[h][ht] - mx) : 0.f;
        float exm = (ht < 128 && !flagL[h][ht]) ? ex : 0.f;
        float sv = ex, sm = exm;
#pragma unroll
        for (int off = 32; off > 0; off >>= 1) {
            sv += __shfl_xor(sv, off);
            sm += __shfl_xor(sm, off);
        }
        __syncthreads();
        if (lane == 0) { red[wv] = sv; red2[wv] = sm; }
        __syncthreads();
        float sum = red[h * 4 + 0] + red[h * 4 + 1] + red[h * 4 + 2] + red[h * 4 + 3];
        pmask = (red2[h * 4 + 0] + red2[h * 4 + 1] + red2[h * 4 + 2] + red2[h * 4 + 3]) / sum;
        if (ht < 128) probsL[h][ht] = ex / sum;
    }
    __syncthreads();

    // ---- o_active: probs-weighted Cj from registers, shfl-tree reduce ----
    {
        float4 op = make_float4(0.f, 0.f, 0.f, 0.f);
        if (mA >= 0) {
            float pa = probsL[h][mA];
            op.x = pa * aC_A.x; op.y = pa * aC_A.y;
            op.z = pa * aC_A.z; op.w = pa * aC_A.w;
        }
        if (mB >= 0) {
            float pb = probsL[h][mB];
            op.x = fmaf(pb, aC_B.x, op.x); op.y = fmaf(pb, aC_B.y, op.y);
            op.z = fmaf(pb, aC_B.z, op.z); op.w = fmaf(pb, aC_B.w, op.w);
        }
#pragma unroll
        for (int off = 4; off <= 32; off <<= 1) {
            op.x += __shfl_xor(op.x, off);
            op.y += __shfl_xor(op.y, off);
            op.z += __shfl_xor(op.z, off);
            op.w += __shfl_xor(op.w, off);
        }
        if (lane < 4) *(float4*)&owaveL[wv * 16 + lane * 4] = op;
    }
    __syncthreads();
    if (ht < 16) {
        float o = owaveL[(h * 4 + 0) * 16 + ht] + owaveL[(h * 4 + 1) * 16 + ht]
                + owaveL[(h * 4 + 2) * 16 + ht] + owaveL[(h * 4 + 3) * 16 + ht];
        uoL[h][ht] = uL[h][ht] + o + cC[ht] * pmask;
    }
    __syncthreads();

    // ---- x = relu(uo @ W_out) (half-lo); xg = relu((u_g + cC) @ W_out) (half-hi) ----
    if (ht < 128) {
        float acc = 0.f;
#pragma unroll
        for (int e = 0; e < 16; e++) acc = fmaf(uoL[h][e], wout[e * 128 + ht], acc);
        xL[h][ht] = fmaxf(acc, 0.f);
    } else {
        int l = ht - 128;
        float acc = 0.f;
#pragma unroll
        for (int e = 0; e < 16; e++) acc = fmaf(ugL[h][e] + cC[e], wout[e * 128 + l], acc);
        xgL[h][l] = fmaxf(acc, 0.f);
    }
    __syncthreads();

    // ---- ret = x @ W_fin (half-lo); ret127 = xg @ W_fin (half-hi); out = sum ----
    {
        const int vcol = ht & 127;
        const float* xsrc = (ht < 128) ? xL[h] : xgL[h];   // wave-uniform base
        float acc = 0.f;
        for (int l = 0; l < 128; l++) acc = fmaf(xsrc[l], wfin[l * 128 + vcol], acc);
        if (ht >= 128) xg2L[h][vcol] = acc;
        __syncthreads();
        if (ht < 128) out[(size_t)bt * 128 + vcol] = acc + xg2L[h][vcol];
    }
}

extern "C" void kernel_launch(void* const* d_in, const int* in_sizes, int n_in,
                              void* d_out, int out_size, void* d_ws, size_t ws_size,
                              hipStream_t stream)
{
    const float* node  = (const float*)d_in[0];
    const float* edge  = (const float*)d_in[1];
    const float* graph = (const float*)d_in[2];
    const float* adjm  = (const float*)d_in[3];
    // d_in[4] = hidden (unused)
    const float* enc   = (const float*)d_in[5];
    const float* qb    = (const float*)d_in[6];
    const float* sb    = (const float*)d_in[7];
    const float* ob    = (const float*)d_in[8];
    const float* mc    = (const float*)d_in[9];
    // d_in[10] = W_int (unused, num_hops == 1)
    const float* wout  = (const float*)d_in[11];
    const float* wfin  = (const float*)d_in[12];

    memnet_fused<<<NBLK, 512, 0, stream>>>(node, edge, graph, adjm, enc, qb,
                                           sb, ob, mc, wout, wfin, (float*)d_out);
}

// Round 6
// 132.317 us; speedup vs baseline: 2.9893x; 1.0277x over previous
//
#include <hip/hip_runtime.h>

// Problem constants
#define Vn 128
#define Sn 32
#define En 16
#define M0 128
#define Ln 128
#define Bn 16
#define Nn 127
#define NROWS (Bn * Nn)     // 2032 blocks, one row each
#define RS 20               // sb table row stride (dwords), 16B-aligned

__global__ __launch_bounds__(256, 8) void memnet_fused(
    const float* __restrict__ node_fts, const float* __restrict__ edge_fts,
    const float* __restrict__ graph_fts, const float* __restrict__ adjm,
    const float* __restrict__ enc, const float* __restrict__ qb,
    const float* __restrict__ sb, const float* __restrict__ ob,
    const float* __restrict__ mc, const float* __restrict__ wout,
    const float* __restrict__ wfin, float* __restrict__ out)
{
    __shared__ __align__(16) float sbL[M0 * RS];    // sb rows (row 127 = nil zeros), LDS
    __shared__ __align__(16) float encL[Sn * En];
    __shared__ unsigned int idxw[M0 * 8];           // 32 uint8 idx per slot, packed
    __shared__ float scoresL[M0];
    __shared__ float probsL[M0];
    __shared__ float uL[En];
    __shared__ float ugL[En];
    __shared__ float uoL[En];
    __shared__ float cM[En];    // sb[0][e] * sum_s enc[s][e]
    __shared__ float cC[En];    // ob[0][e] * sum_s enc[s][e]
    __shared__ float xL[Ln];
    __shared__ float xgL[Ln];
    __shared__ float xg2L[Vn];
    __shared__ float owaveL[4 * En];
    __shared__ float red[4], red2[4];
    __shared__ int listL[128];
    __shared__ int flagL[128];
    __shared__ int wcnt[2];

    const int t = threadIdx.x;
    const int bt = blockIdx.x;          // output row == b*127 + i
    const int b = bt / 127;
    const int lane = t & 63;
    const int wv = t >> 6;

    // ---- stage sb table into LDS (ob stays in L1/L2 — read directly in gather) ----
    for (int c = t; c < 512; c += 256) {
        int r = c >> 2, q = c & 3;
        float4 v = make_float4(0.f, 0.f, 0.f, 0.f);
        if (r < 127) v = *(const float4*)&sb[r * 16 + q * 4];
        *(float4*)&sbL[r * RS + q * 4] = v;
    }
    if (t < 128) *(float4*)&encL[t * 4] = *(const float4*)&enc[t * 4];

    // ---- active flags + ballot-compacted slot list ----
    if (t < 128) {
        bool flag = (t < 127) && (adjm[(size_t)bt * 127 + t] != 0.f);
        unsigned long long msk = __ballot(flag);
        int pos = (int)__popcll(msk & ((1ull << lane) - 1ull));
        if (flag) listL[(t & 64) + pos] = t;   // wave0 -> [0..), wave1 -> [64..)
        if (lane == 0) wcnt[t >> 6] = (int)__popcll(msk);
        flagL[t] = flag ? 1 : 0;
    }
    // ---- index tile for active slots only (coalesced streaming read) ----
    for (int c = t; c < 1024; c += 256) {
        int m = c >> 3, q = c & 7;
        if (m < 127 && adjm[(size_t)bt * 127 + m] != 0.f) {
            float4 v = *(const float4*)&edge_fts[(size_t)(bt * 127 + m) * 32 + q * 4];
            idxw[m * 8 + q] = (unsigned)(int)v.x | ((unsigned)(int)v.y << 8)
                            | ((unsigned)(int)v.z << 16) | ((unsigned)(int)v.w << 24);
        }
    }
    // ---- u (wave0), u_g (wave2), cM/cC (wave1) ----
    if (lane < 16) {
        if (wv == 0) {
            float ue = 0.f;
            for (int s = 0; s < 32; s++) {
                int qi = (int)node_fts[(size_t)bt * 32 + s];
                if (qi < 0) qi = 0;
                float w = (qi < 127) ? qb[qi * 16 + lane] : 0.f;
                ue = fmaf(w, enc[s * 16 + lane], ue);
            }
            uL[lane] = ue;
        } else if (wv == 2) {
            float ue = 0.f;
            for (int s = 0; s < 32; s++) {
                int qi = (int)graph_fts[b * 32 + s];
                if (qi < 0) qi = 0;
                float w = (qi < 127) ? qb[qi * 16 + lane] : 0.f;
                ue = fmaf(w, enc[s * 16 + lane], ue);
            }
            ugL[lane] = ue;
        } else if (wv == 1) {
            float es = 0.f;
            for (int s = 0; s < 32; s++) es += enc[s * 16 + lane];
            cM[lane] = sb[lane] * es;   // vocab row 0
            cC[lane] = ob[lane] * es;
        }
    }
    __syncthreads();

    // ---- masked/pad slots: closed-form scores ----
    if (t < 128 && !flagL[t]) {
        float p = 0.f;
#pragma unroll
        for (int e4 = 0; e4 < 16; e4 += 4) {
            float4 m4 = *(const float4*)&mc[t * 16 + e4];
            p = fmaf(cM[e4 + 0] + m4.x, uL[e4 + 0], p);
            p = fmaf(cM[e4 + 1] + m4.y, uL[e4 + 1], p);
            p = fmaf(cM[e4 + 2] + m4.z, uL[e4 + 2], p);
            p = fmaf(cM[e4 + 3] + m4.w, uL[e4 + 3], p);
        }
        scoresL[t] = p;
    }

    // ---- gather: one active slot per quad; sb from LDS, ob from L1/global ----
    const int eg4 = (t & 3) * 4;
    const int qd = t >> 2;              // quad id 0..63
    const int c0 = wcnt[0];
    const int nact = c0 + wcnt[1];
    const float4 u4 = *(const float4*)&uL[eg4];

    float4 aC_A = make_float4(0.f, 0.f, 0.f, 0.f);
    float4 aC_B = make_float4(0.f, 0.f, 0.f, 0.f);
    int mA = -1, mB = -1;

    if (qd < nact) {
        mA = listL[(qd < c0) ? qd : (qd - c0 + 64)];
        float4 aM = make_float4(0.f, 0.f, 0.f, 0.f);
        for (int sq = 0; sq < 8; sq++) {
            unsigned w0 = idxw[mA * 8 + sq];
#pragma unroll
            for (int j = 0; j < 4; j++) {
                int s = sq * 4 + j;
                int i0 = (w0 >> (8 * j)) & 0xFF;
                int i0c = (i0 < 127) ? i0 : 126;            // clamp for in-bounds load
                float4 eb = *(const float4*)&encL[s * 16 + eg4];
                float4 a0 = *(const float4*)&sbL[i0 * RS + eg4];
                float4 cv = *(const float4*)&ob[i0c * 16 + eg4];  // L1-resident (8 KB)
                if (i0 == 127) cv = make_float4(0.f, 0.f, 0.f, 0.f);  // nil row
                aM.x = fmaf(a0.x, eb.x, aM.x); aM.y = fmaf(a0.y, eb.y, aM.y);
                aM.z = fmaf(a0.z, eb.z, aM.z); aM.w = fmaf(a0.w, eb.w, aM.w);
                aC_A.x = fmaf(cv.x, eb.x, aC_A.x); aC_A.y = fmaf(cv.y, eb.y, aC_A.y);
                aC_A.z = fmaf(cv.z, eb.z, aC_A.z); aC_A.w = fmaf(cv.w, eb.w, aC_A.w);
            }
        }
        float4 mc4 = *(const float4*)&mc[mA * 16 + eg4];
        float p = (aM.x + mc4.x) * u4.x + (aM.y + mc4.y) * u4.y
                + (aM.z + mc4.z) * u4.z + (aM.w + mc4.w) * u4.w;
        p += __shfl_xor(p, 1); p += __shfl_xor(p, 2);
        if ((t & 3) == 0) scoresL[mA] = p;
    }
    if (qd + 64 < nact) {   // overflow slots (nact > 64)
        int g = qd + 64;
        mB = listL[(g < c0) ? g : (g - c0 + 64)];
        float4 aM = make_float4(0.f, 0.f, 0.f, 0.f);
        for (int sq = 0; sq < 8; sq++) {
            unsigned w0 = idxw[mB * 8 + sq];
#pragma unroll
            for (int j = 0; j < 4; j++) {
                int s = sq * 4 + j;
                int i0 = (w0 >> (8 * j)) & 0xFF;
                int i0c = (i0 < 127) ? i0 : 126;
                float4 eb = *(const float4*)&encL[s * 16 + eg4];
                float4 a0 = *(const float4*)&sbL[i0 * RS + eg4];
                float4 cv = *(const float4*)&ob[i0c * 16 + eg4];
                if (i0 == 127) cv = make_float4(0.f, 0.f, 0.f, 0.f);
                aM.x = fmaf(a0.x, eb.x, aM.x); aM.y = fmaf(a0.y, eb.y, aM.y);
                aM.z = fmaf(a0.z, eb.z, aM.z); aM.w = fmaf(a0.w, eb.w, aM.w);
                aC_B.x = fmaf(cv.x, eb.x, aC_B.x); aC_B.y = fmaf(cv.y, eb.y, aC_B.y);
                aC_B.z = fmaf(cv.z, eb.z, aC_B.z); aC_B.w = fmaf(cv.w, eb.w, aC_B.w);
            }
        }
        float4 mc4 = *(const float4*)&mc[mB * 16 + eg4];
        float p = (aM.x + mc4.x) * u4.x + (aM.y + mc4.y) * u4.y
                + (aM.z + mc4.z) * u4.z + (aM.w + mc4.w) * u4.w;
        p += __shfl_xor(p, 1); p += __shfl_xor(p, 2);
        if ((t & 3) == 0) scoresL[mB] = p;
    }
    __syncthreads();

    // ---- softmax over 128 slots (+ masked prob mass in same reduction) ----
    float pmask;
    {
        float v = (t < 128) ? scoresL[t] : -1e30f;
#pragma unroll
        for (int off = 32; off > 0; off >>= 1) v = fmaxf(v, __shfl_xor(v, off));
        if (lane == 0) red[wv] = v;
        __syncthreads();
        float mx = fmaxf(fmaxf(red[0], red[1]), fmaxf(red[2], red[3]));
        float ex = (t < 128) ? __expf(scoresL[t] - mx) : 0.f;
        float exm = (t < 128 && !flagL[t]) ? ex : 0.f;
        float sv = ex, sm = exm;
#pragma unroll
        for (int off = 32; off > 0; off >>= 1) {
            sv += __shfl_xor(sv, off);
            sm += __shfl_xor(sm, off);
        }
        __syncthreads();
        if (lane == 0) { red[wv] = sv; red2[wv] = sm; }
        __syncthreads();
        float sum = red[0] + red[1] + red[2] + red[3];
        pmask = (red2[0] + red2[1] + red2[2] + red2[3]) / sum;
        if (t < 128) probsL[t] = ex / sum;
    }
    __syncthreads();

    // ---- o_active: probs-weighted Cj from registers, shfl-tree reduce ----
    {
        float4 op = make_float4(0.f, 0.f, 0.f, 0.f);
        if (mA >= 0) {
            float pa = probsL[mA];
            op.x = pa * aC_A.x; op.y = pa * aC_A.y;
            op.z = pa * aC_A.z; op.w = pa * aC_A.w;
        }
        if (mB >= 0) {
            float pb = probsL[mB];
            op.x = fmaf(pb, aC_B.x, op.x); op.y = fmaf(pb, aC_B.y, op.y);
            op.z = fmaf(pb, aC_B.z, op.z); op.w = fmaf(pb, aC_B.w, op.w);
        }
#pragma unroll
        for (int off = 4; off <= 32; off <<= 1) {
            op.x += __shfl_xor(op.x, off);
            op.y += __shfl_xor(op.y, off);
            op.z += __shfl_xor(op.z, off);
            op.w += __shfl_xor(op.w, off);
        }
        if (lane < 4) *(float4*)&owaveL[wv * 16 + lane * 4] = op;
    }
    __syncthreads();
    if (t < 16) {
        float o = owaveL[t] + owaveL[16 + t] + owaveL[32 + t] + owaveL[48 + t];
        uoL[t] = uL[t] + o + cC[t] * pmask;
    }
    __syncthreads();

    // ---- x = relu(uo @ W_out) (half 0); xg = relu((u_g + cC) @ W_out) (half 1) ----
    if (t < 128) {
        float acc = 0.f;
#pragma unroll
        for (int e = 0; e < 16; e++) acc = fmaf(uoL[e], wout[e * 128 + t], acc);
        xL[t] = fmaxf(acc, 0.f);
    } else {
        int l = t - 128;
        float acc = 0.f;
#pragma unroll
        for (int e = 0; e < 16; e++) acc = fmaf(ugL[e] + cC[e], wout[e * 128 + l], acc);
        xgL[l] = fmaxf(acc, 0.f);
    }
    __syncthreads();

    // ---- ret = x @ W_fin (half 0); ret127 = xg @ W_fin (half 1); out = sum ----
    {
        const int vcol = t & 127;
        const float* xsrc = (t < 128) ? xL : xgL;   // wave-uniform base
        float acc = 0.f;
        for (int l = 0; l < 128; l++) acc = fmaf(xsrc[l], wfin[l * 128 + vcol], acc);
        if (t >= 128) xg2L[vcol] = acc;
        __syncthreads();
        if (t < 128) out[(size_t)bt * 128 + vcol] = acc + xg2L[vcol];
    }
}

extern "C" void kernel_launch(void* const* d_in, const int* in_sizes, int n_in,
                              void* d_out, int out_size, void* d_ws, size_t ws_size,
                              hipStream_t stream)
{
    const float* node  = (const float*)d_in[0];
    const float* edge  = (const float*)d_in[1];
    const float* graph = (const float*)d_in[2];
    const float* adjm  = (const float*)d_in[3];
    // d_in[4] = hidden (unused)
    const float* enc   = (const float*)d_in[5];
    const float* qb    = (const float*)d_in[6];
    const float* sb    = (const float*)d_in[7];
    const float* ob    = (const float*)d_in[8];
    const float* mc    = (const float*)d_in[9];
    // d_in[10] = W_int (unused, num_hops == 1)
    const float* wout  = (const float*)d_in[11];
    const float* wfin  = (const float*)d_in[12];

    memnet_fused<<<NROWS, 256, 0, stream>>>(node, edge, graph, adjm, enc, qb,
                                            sb, ob, mc, wout, wfin, (float*)d_out);
}